// Round 14
// baseline (1196.437 us; speedup 1.0000x reference)
//
#include <hip/hip_runtime.h>

#define BB 256
#define TT 256
#define NN 512
#define HH 512

typedef short short8 __attribute__((ext_vector_type(8)));
typedef float f32x4 __attribute__((ext_vector_type(4)));
typedef unsigned long long u64;

static __device__ __forceinline__ ushort f2bf(float f) {
  uint b = __builtin_bit_cast(uint, f);
  b += 0x7FFFu + ((b >> 16) & 1u);
  return (ushort)(b >> 16);
}
static __device__ __forceinline__ uint pk2(float lo, float hi) {
  return (uint)f2bf(lo) | ((uint)f2bf(hi) << 16);
}
static __device__ __forceinline__ float sigm_(float x) {
  return 1.0f / (1.0f + exp2f(-1.4426950408889634f * x));
}
static __device__ __forceinline__ float tanh_(float x) {
  return 2.0f / (1.0f + exp2f(-2.8853900817779268f * x)) - 1.0f;
}
// raw barrier: LDS ordering only (no vmcnt drain)
static __device__ __forceinline__ void bar_lds() {
  asm volatile("s_waitcnt lgkmcnt(0)" ::: "memory");
  __builtin_amdgcn_s_barrier();
}

// ---------------------------------------------------------------------------
// Prep: W2 = [w_ih | w_hh] bf16 (2048 x 1024), b_gate = b_ih + b_hh,
// h0 -> tagged slot1 words (tag 0): u64 = 0<<32 | bf16x2 pair.
// ---------------------------------------------------------------------------
__global__ __launch_bounds__(256) void prep_kernel(
    const float* __restrict__ w_ih, const float* __restrict__ w_hh,
    const float* __restrict__ b_ih, const float* __restrict__ b_hh,
    const float* __restrict__ h0,
    ushort* __restrict__ W2, float* __restrict__ bgate,
    u64* __restrict__ hs1) {
  int idx = blockIdx.x * 256 + threadIdx.x;
  if (idx < 2048 * 1024) {
    int row = idx >> 10;
    int k = idx & 1023;
    float v = (k < NN) ? w_ih[row * NN + k] : w_hh[row * HH + (k - NN)];
    W2[idx] = f2bf(v);
  }
  if (idx < 2048) bgate[idx] = b_ih[idx] + b_hh[idx];
  if (idx < BB * HH / 2)
    hs1[idx] = (u64)pk2(h0[2 * idx], h0[2 * idx + 1]);  // tag 0 in hi32
}

// ---------------------------------------------------------------------------
// Attention + ax precompute (a = softmax_n(proj_x), timestep-invariant by
// softmax shift invariance). Pass 2 writes bf16 ax into the borrowed
// attentions output region; attn_out itself written by bcast_kernel.
// ---------------------------------------------------------------------------
__global__ __launch_bounds__(256) void attn_kernel(
    const float* __restrict__ x, const float* __restrict__ attn_w,
    float* __restrict__ a_out, ushort* __restrict__ ax) {
  __shared__ float wx[TT];
  __shared__ float as[NN];
  __shared__ float red[8];
  const int b = blockIdx.x;
  const int tid = threadIdx.x;
  wx[tid] = attn_w[2 * HH + tid];
  __syncthreads();

  const float* xb = x + (size_t)b * TT * NN;
  float p0 = 0.0f, p1 = 0.0f;
  for (int t = 0; t < TT; ++t) {
    float w = wx[t];
    p0 += xb[t * NN + tid] * w;
    p1 += xb[t * NN + 256 + tid] * w;
  }

  const int lane = tid & 63, wv = tid >> 6;
  float m = fmaxf(p0, p1);
  #pragma unroll
  for (int o = 32; o; o >>= 1) m = fmaxf(m, __shfl_xor(m, o));
  if (lane == 0) red[wv] = m;
  __syncthreads();
  m = fmaxf(fmaxf(red[0], red[1]), fmaxf(red[2], red[3]));
  float e0 = expf(p0 - m), e1 = expf(p1 - m);
  float s = e0 + e1;
  #pragma unroll
  for (int o = 32; o; o >>= 1) s += __shfl_xor(s, o);
  if (lane == 0) red[4 + wv] = s;
  __syncthreads();
  s = red[4] + red[5] + red[6] + red[7];
  float inv = 1.0f / s;
  float a0 = e0 * inv, a1 = e1 * inv;
  a_out[b * NN + tid] = a0;
  a_out[b * NN + 256 + tid] = a1;
  as[tid] = a0;
  as[tid + 256] = a1;
  __syncthreads();

  const float aa0 = as[tid * 2], aa1 = as[tid * 2 + 1];
  ushort* axb = ax + (size_t)b * TT * NN;
  for (int t = 0; t < TT; ++t) {
    const float2 xv = *(const float2*)(xb + t * NN + tid * 2);
    *(uint*)(axb + t * NN + tid * 2) = pk2(aa0 * xv.x, aa1 * xv.y);
  }
}

// ---------------------------------------------------------------------------
// Final: broadcast a over t into the attentions output.
// ---------------------------------------------------------------------------
__global__ __launch_bounds__(256) void bcast_kernel(
    const float* __restrict__ a, float* __restrict__ attn_out) {
  const size_t idx = (size_t)blockIdx.x * 256 + threadIdx.x;
  const int n4 = (int)(idx & 127);
  const int t = (int)((idx >> 7) & 255);
  const int b = (int)(idx >> 15);
  const float4 v = *(const float4*)(a + b * NN + n4 * 4);
  *(float4*)(attn_out + (((size_t)b * TT + t) * NN + n4 * 4)) = v;
}

// ---------------------------------------------------------------------------
// Persistent LSTM v14 = v10 data path + TAGGED h-exchange (2 MALL hops/step
// instead of 4):
//  * h word = u64: hi32 = tag (t+1), lo32 = bf16x2 pair. Producer: ONE
//    relaxed agent 8B atomic store per pair -- no vmcnt ack, no signal
//    atomic, no arrive aggregation (word self-describes readiness; 8B
//    global atomics are single-copy atomic so tag+data arrive together).
//  * Consumer threads poll their OWN 8 words (relaxed agent 8B loads,
//    MALL-direct) until all tags == t; first poll hidden under x-half MFMAs.
//  * 2 slots (even/odd t); tag disambiguates generations. Cross-replay
//    leftovers: either tag-mismatched or bit-identical (deterministic
//    recompute of same inputs) -> correct. Slot overwrite at t+2 provably
//    follows all reads of t (producer observed tags of t+1 first).
//  * Poll has a 2^18-spin safety exit: a logic bug fails fast with large
//    absmax instead of a 600s hang (round-11 lesson).
// Sync state (warr/step_flag/bar) deleted; one uniform path for all waves.
// ---------------------------------------------------------------------------
__global__ __launch_bounds__(512, 2) void lstm_persistent(
    const ushort* __restrict__ ax,   // (B,T,N) bf16 = a*x
    const ushort* __restrict__ W2,   // (2048,1024) bf16
    const float* __restrict__ bgate, // (2048)
    const float* __restrict__ c0,    // (B,H)
    u64* __restrict__ hs0,           // slot0: (B, H/2) tagged words
    u64* __restrict__ hs1,           // slot1: (B, H/2) tagged words (h0@tag0)
    float* __restrict__ enc) {       // (B,T,H)
  __shared__ ushort hx[16 * 1024];  // 32 KB panel [16 batch][1024 k], swizzled

  const int tid = threadIdx.x;
  const int lane = tid & 63;
  const int w = tid >> 6;
  const int bg = blockIdx.x & 15;   // XCD-local group
  const int jt = blockIdx.x >> 4;
  const int gb0 = bg * 16;

  // ---- W2 A-fragments: areg[i] = k-chunk i (uniform across lanes)
  f32x4 areg[32];
  {
    const int r = lane & 15;
    const int grow = (r & 3) * 512 + jt * 32 + w * 4 + (r >> 2);
    const ushort* wp = W2 + (size_t)grow * 1024 + ((lane >> 4) << 3);
    #pragma unroll
    for (int i = 0; i < 32; ++i) {
      areg[i] = *(const f32x4*)(wp + (i << 5));
      asm volatile("" : "+v"(areg[i]));
    }
  }

  // ---- staging geometry: thread = (srow 0..15, sl 0..31)
  const int srow = tid >> 5;
  const int sl = tid & 31;
  const int r7 = srow & 7;

  // ---- per-lane output geometry: (batch eb, col ecol), 4 gates in acc[0..3]
  const int eb = lane & 15;
  const int kq = lane >> 4;
  const int ecol = jt * 32 + w * 4 + kq;
  const float bgi = bgate[ecol];
  const float bgf = bgate[512 + ecol];
  const float bgg = bgate[1024 + ecol];
  const float bgo = bgate[1536 + ecol];
  float c_reg = c0[(size_t)(gb0 + eb) * HH + ecol];

  // ---- MFMA B-read geometry (proven per-iteration XOR addressing)
  const int bbase = (lane & 15) * 1024;
  const int br7 = (lane & 15) & 7;

  // ---- tagged-word addresses (consumer: own row srow; producer: own pair)
  const size_t crow = (size_t)(gb0 + srow) * 256 + sl * 4;
  const size_t pword = (size_t)(gb0 + eb) * 256 + (ecol >> 1);

  // ---- x prefetch for t=0
  uint4 px0, px1;
  {
    const ushort* axp = ax + ((size_t)(gb0 + srow) * TT + 0) * NN;
    px0 = *(const uint4*)(axp + sl * 8);
    px1 = *(const uint4*)(axp + 256 + sl * 8);
  }

  for (int t = 0; t < TT; ++t) {
    // slot holding h(t-1) = (t+1)&1 [h0 in slot1]; produce into slot t&1
    const u64* hin = (((t + 1) & 1) ? hs1 : hs0) + crow;
    u64* hout = ((t & 1) ? hs1 : hs0) + pword;
    const uint exptag = (uint)t;

    // ---- stage x-part from prefetch regs; issue prefetch for t+1
    *(uint4*)&hx[srow * 1024 + ((sl ^ r7) << 3)] = px0;
    *(uint4*)&hx[srow * 1024 + (((32 + sl) ^ r7) << 3)] = px1;
    if (t + 1 < TT) {
      const ushort* axp = ax + ((size_t)(gb0 + srow) * TT + (t + 1)) * NN;
      px0 = *(const uint4*)(axp + sl * 8);
      px1 = *(const uint4*)(axp + 256 + sl * 8);
    }
    bar_lds();  // B1: x-panel ready

    // ---- issue first poll round (flies under the x-half MFMAs)
    u64 v[8];
    #pragma unroll
    for (int i = 0; i < 4; ++i)
      v[i] = __hip_atomic_load(hin + i, __ATOMIC_RELAXED,
                               __HIP_MEMORY_SCOPE_AGENT);
    #pragma unroll
    for (int i = 0; i < 4; ++i)
      v[4 + i] = __hip_atomic_load(hin + 128 + i, __ATOMIC_RELAXED,
                                   __HIP_MEMORY_SCOPE_AGENT);

    // ---- x-half MFMAs (no h dependency)
    f32x4 acc = {0.f, 0.f, 0.f, 0.f};
    #pragma unroll
    for (int ks = 0; ks < 16; ++ks) {
      const int ag = ks * 4 + kq;
      const short8 bf = *(const short8*)&hx[bbase + ((ag ^ br7) << 3)];
      acc = __builtin_amdgcn_mfma_f32_16x16x32_bf16(
          __builtin_bit_cast(short8, areg[ks]), bf, acc, 0, 0, 0);
    }

    // ---- poll: all 8 own words must carry tag t (safety-bounded)
    {
      int spins = 0;
      for (;;) {
        uint ok = 1;
        #pragma unroll
        for (int i = 0; i < 8; ++i) ok &= ((uint)(v[i] >> 32) == exptag);
        if (ok) break;
        if (++spins > (1 << 18)) break;  // fail fast, never hang
        __builtin_amdgcn_s_sleep(1);
        #pragma unroll
        for (int i = 0; i < 4; ++i)
          v[i] = __hip_atomic_load(hin + i, __ATOMIC_RELAXED,
                                   __HIP_MEMORY_SCOPE_AGENT);
        #pragma unroll
        for (int i = 0; i < 4; ++i)
          v[4 + i] = __hip_atomic_load(hin + 128 + i, __ATOMIC_RELAXED,
                                       __HIP_MEMORY_SCOPE_AGENT);
      }
    }

    // ---- stage h-part from tagged words (lo32 = bf16x2 data)
    {
      uint4 p0, p1;
      p0.x = (uint)v[0]; p0.y = (uint)v[1]; p0.z = (uint)v[2]; p0.w = (uint)v[3];
      p1.x = (uint)v[4]; p1.y = (uint)v[5]; p1.z = (uint)v[6]; p1.w = (uint)v[7];
      *(uint4*)&hx[srow * 1024 + (((64 + sl) ^ r7) << 3)] = p0;
      *(uint4*)&hx[srow * 1024 + (((96 + sl) ^ r7) << 3)] = p1;
    }
    bar_lds();  // B2: h-panel ready

    // ---- h-half MFMAs
    #pragma unroll
    for (int ks = 16; ks < 32; ++ks) {
      const int ag = ks * 4 + kq;
      const short8 bf = *(const short8*)&hx[bbase + ((ag ^ br7) << 3)];
      acc = __builtin_amdgcn_mfma_f32_16x16x32_bf16(
          __builtin_bit_cast(short8, areg[ks]), bf, acc, 0, 0, 0);
    }

    // ---- in-lane LSTM cell; publish tagged h (no ack, no signal)
    {
      const float ig = sigm_(acc[0] + bgi);
      const float fg = sigm_(acc[1] + bgf);
      const float gg = tanh_(acc[2] + bgg);
      const float og = sigm_(acc[3] + bgo);
      const float cn = fg * c_reg + ig * gg;
      const float hn = og * tanh_(cn);
      c_reg = cn;
      const float hp_ = __shfl_xor(hn, 16);   // partner col (kq^1)
      if (!(lane & 16)) {                     // kq even lanes store the pair
        const u64 word = ((u64)(uint)(t + 1) << 32) | (u64)pk2(hn, hp_);
        __hip_atomic_store(hout, word, __ATOMIC_RELAXED,
                           __HIP_MEMORY_SCOPE_AGENT);
      }
      enc[((size_t)(gb0 + eb) * TT + t) * HH + ecol] = hn;  // never drained
    }
  }
}

extern "C" void kernel_launch(void* const* d_in, const int* in_sizes, int n_in,
                              void* d_out, int out_size, void* d_ws, size_t ws_size,
                              hipStream_t stream) {
  const float* x      = (const float*)d_in[0];
  const float* h0     = (const float*)d_in[1];
  const float* c0     = (const float*)d_in[2];
  const float* attn_w = (const float*)d_in[3];
  // d_in[4] = attn_b: softmax-shift-invariant -> unused
  const float* w_ih   = (const float*)d_in[5];
  const float* w_hh   = (const float*)d_in[6];
  const float* b_ih   = (const float*)d_in[7];
  const float* b_hh   = (const float*)d_in[8];

  float* attn_out = (float*)d_out;                         // (B,T,N)
  float* enc_out  = (float*)d_out + (size_t)BB * TT * NN;  // (B,T,H)
  // borrow the attn output region for bf16 ax (64 MB of 128 MB) until bcast
  ushort* ax = (ushort*)d_out;

  char* ws = (char*)d_ws;
  float*  a_ws  = (float*)(ws);                    // 512 KB
  ushort* W2_ws = (ushort*)(ws + 0x80000);         // 4 MB
  float*  bg_ws = (float*)(ws + 0x480000);         // 8 KB
  u64*    hs0   = (u64*)(ws + 0x482000);           // 512 KB tagged slot0
  u64*    hs1   = (u64*)(ws + 0x502000);           // 512 KB tagged slot1

  prep_kernel<<<8192, 256, 0, stream>>>(w_ih, w_hh, b_ih, b_hh, h0,
                                        W2_ws, bg_ws, hs1);
  attn_kernel<<<BB, 256, 0, stream>>>(x, attn_w, a_ws, ax);

  {
    dim3 grid(256), block(512);
    void* args[] = {(void*)&ax, (void*)&W2_ws, (void*)&bg_ws, (void*)&c0,
                    (void*)&hs0, (void*)&hs1, (void*)&enc_out};
    hipLaunchCooperativeKernel((void*)lstm_persistent, grid, block, args, 0,
                               stream);
  }

  bcast_kernel<<<32768, 256, 0, stream>>>(a_ws, attn_out);
}

// Round 15
// 860.805 us; speedup vs baseline: 1.3899x; 1.3899x over previous
//
#include <hip/hip_runtime.h>

#define BB 256
#define TT 256
#define NN 512
#define HH 512

typedef short short8 __attribute__((ext_vector_type(8)));
typedef float f32x4 __attribute__((ext_vector_type(4)));
typedef unsigned long long u64;

static __device__ __forceinline__ ushort f2bf(float f) {
  uint b = __builtin_bit_cast(uint, f);
  b += 0x7FFFu + ((b >> 16) & 1u);
  return (ushort)(b >> 16);
}
static __device__ __forceinline__ uint pk2(float lo, float hi) {
  return (uint)f2bf(lo) | ((uint)f2bf(hi) << 16);
}
static __device__ __forceinline__ float sigm_(float x) {
  return 1.0f / (1.0f + exp2f(-1.4426950408889634f * x));
}
static __device__ __forceinline__ float tanh_(float x) {
  return 2.0f / (1.0f + exp2f(-2.8853900817779268f * x)) - 1.0f;
}
// raw barrier: LDS ordering only (no vmcnt drain)
static __device__ __forceinline__ void bar_lds() {
  asm volatile("s_waitcnt lgkmcnt(0)" ::: "memory");
  __builtin_amdgcn_s_barrier();
}

// ---------------------------------------------------------------------------
// Prep: W2 = [w_ih | w_hh] bf16 (2048 x 1024), b_gate = b_ih + b_hh,
// h0 packed bf16x2 -> hx16a, zero padded tag lines (every launch).
// ---------------------------------------------------------------------------
__global__ __launch_bounds__(256) void prep_kernel(
    const float* __restrict__ w_ih, const float* __restrict__ w_hh,
    const float* __restrict__ b_ih, const float* __restrict__ b_hh,
    const float* __restrict__ h0,
    ushort* __restrict__ W2, float* __restrict__ bgate,
    uint* __restrict__ hx16a, unsigned* __restrict__ bar) {
  int idx = blockIdx.x * 256 + threadIdx.x;
  if (idx < 2048 * 1024) {
    int row = idx >> 10;
    int k = idx & 1023;
    float v = (k < NN) ? w_ih[row * NN + k] : w_hh[row * HH + (k - NN)];
    W2[idx] = f2bf(v);
  }
  if (idx < 2048) bgate[idx] = b_ih[idx] + b_hh[idx];
  if (idx < BB * HH / 2) hx16a[idx] = pk2(h0[2 * idx], h0[2 * idx + 1]);
  if (idx < 16 * 64) bar[idx] = 0u;
}

// ---------------------------------------------------------------------------
// Attention + ax precompute (a = softmax_n(proj_x), timestep-invariant by
// softmax shift invariance). Pass 2 writes bf16 ax into the borrowed
// attentions output region; attn_out itself written by bcast_kernel.
// ---------------------------------------------------------------------------
__global__ __launch_bounds__(256) void attn_kernel(
    const float* __restrict__ x, const float* __restrict__ attn_w,
    float* __restrict__ a_out, ushort* __restrict__ ax) {
  __shared__ float wx[TT];
  __shared__ float as[NN];
  __shared__ float red[8];
  const int b = blockIdx.x;
  const int tid = threadIdx.x;
  wx[tid] = attn_w[2 * HH + tid];
  __syncthreads();

  const float* xb = x + (size_t)b * TT * NN;
  float p0 = 0.0f, p1 = 0.0f;
  for (int t = 0; t < TT; ++t) {
    float w = wx[t];
    p0 += xb[t * NN + tid] * w;
    p1 += xb[t * NN + 256 + tid] * w;
  }

  const int lane = tid & 63, wv = tid >> 6;
  float m = fmaxf(p0, p1);
  #pragma unroll
  for (int o = 32; o; o >>= 1) m = fmaxf(m, __shfl_xor(m, o));
  if (lane == 0) red[wv] = m;
  __syncthreads();
  m = fmaxf(fmaxf(red[0], red[1]), fmaxf(red[2], red[3]));
  float e0 = expf(p0 - m), e1 = expf(p1 - m);
  float s = e0 + e1;
  #pragma unroll
  for (int o = 32; o; o >>= 1) s += __shfl_xor(s, o);
  if (lane == 0) red[4 + wv] = s;
  __syncthreads();
  s = red[4] + red[5] + red[6] + red[7];
  float inv = 1.0f / s;
  float a0 = e0 * inv, a1 = e1 * inv;
  a_out[b * NN + tid] = a0;
  a_out[b * NN + 256 + tid] = a1;
  as[tid] = a0;
  as[tid + 256] = a1;
  __syncthreads();

  const float aa0 = as[tid * 2], aa1 = as[tid * 2 + 1];
  ushort* axb = ax + (size_t)b * TT * NN;
  for (int t = 0; t < TT; ++t) {
    const float2 xv = *(const float2*)(xb + t * NN + tid * 2);
    *(uint*)(axb + t * NN + tid * 2) = pk2(aa0 * xv.x, aa1 * xv.y);
  }
}

// ---------------------------------------------------------------------------
// Final: broadcast a over t into the attentions output.
// ---------------------------------------------------------------------------
__global__ __launch_bounds__(256) void bcast_kernel(
    const float* __restrict__ a, float* __restrict__ attn_out) {
  const size_t idx = (size_t)blockIdx.x * 256 + threadIdx.x;
  const int n4 = (int)(idx & 127);
  const int t = (int)((idx >> 7) & 255);
  const int b = (int)(idx >> 15);
  const float4 v = *(const float4*)(a + b * NN + n4 * 4);
  *(float4*)(attn_out + (((size_t)b * TT + t) * NN + n4 * 4)) = v;
}

// ---------------------------------------------------------------------------
// Persistent LSTM v15 = v10 (proven, 815us) with ONLY the signal path changed:
//  * signal: producer's last wave (proven warr LDS aggregation) does a PLAIN
//    relaxed agent store of tag=t+1 into its own 4B slot of the bg's 64B tag
//    line -- fire-and-forget, no RMW round trip, no 16-way RMW serialization
//    at the MALL line. Ordering: every wave vmcnt(0)-acks its h-stores
//    before bumping warr; tag store issues only after warr==8.
//  * detect: wave0 lane0 polls the 64B line with TWO read rounds in flight
//    (8 x u64 relaxed loads each, all compile-time indexed) -> effective
//    detect granularity ~halved. Spin-bounded (no hang; round-11 lesson).
// Everything else byte-identical to v10.
// ---------------------------------------------------------------------------
__global__ __launch_bounds__(512, 2) void lstm_persistent(
    const ushort* __restrict__ ax,   // (B,T,N) bf16 = a*x
    const ushort* __restrict__ W2,   // (2048,1024) bf16
    const float* __restrict__ bgate, // (2048)
    const float* __restrict__ c0,    // (B,H)
    uint* __restrict__ hx16a, uint* __restrict__ hx16b,  // (B, H/2) bf16x2
    float* __restrict__ enc,         // (B,T,H)
    unsigned* __restrict__ bar) {
  __shared__ ushort hx[16 * 1024];  // 32 KB panel [16 batch][1024 k], swizzled
  __shared__ unsigned warr;         // monotonic wave-arrive counter
  __shared__ unsigned step_flag;    // poll broadcast (monotonic)

  const int tid = threadIdx.x;
  const int lane = tid & 63;
  const int w = tid >> 6;
  const int bg = blockIdx.x & 15;   // XCD-local group
  const int jt = blockIdx.x >> 4;
  const int gb0 = bg * 16;
  unsigned* const barp = bar + bg * 64;  // 256B-padded 64B tag line (16x4B)

  if (tid == 0) { warr = 0u; step_flag = 0u; }

  // ---- W2 A-fragments: areg[i] = k-chunk i (uniform across lanes)
  f32x4 areg[32];
  {
    const int r = lane & 15;
    const int grow = (r & 3) * 512 + jt * 32 + w * 4 + (r >> 2);
    const ushort* wp = W2 + (size_t)grow * 1024 + ((lane >> 4) << 3);
    #pragma unroll
    for (int i = 0; i < 32; ++i) {
      areg[i] = *(const f32x4*)(wp + (i << 5));
      asm volatile("" : "+v"(areg[i]));
    }
  }

  // ---- staging geometry: thread = (srow 0..15, sl 0..31)
  const int srow = tid >> 5;
  const int sl = tid & 31;
  const int r7 = srow & 7;

  // ---- per-lane output geometry: (batch eb, col ecol), 4 gates in acc[0..3]
  const int eb = lane & 15;
  const int kq = lane >> 4;
  const int ecol = jt * 32 + w * 4 + kq;
  const float bgi = bgate[ecol];
  const float bgf = bgate[512 + ecol];
  const float bgg = bgate[1024 + ecol];
  const float bgo = bgate[1536 + ecol];
  float c_reg = c0[(size_t)(gb0 + eb) * HH + ecol];

  // ---- MFMA B-read geometry (proven per-iteration XOR addressing)
  const int bbase = (lane & 15) * 1024;
  const int br7 = (lane & 15) & 7;

  // ---- x prefetch for t=0
  uint4 px0, px1;
  {
    const ushort* axp = ax + ((size_t)(gb0 + srow) * TT + 0) * NN;
    px0 = *(const uint4*)(axp + sl * 8);
    px1 = *(const uint4*)(axp + 256 + sl * 8);
  }

  for (int t = 0; t < TT; ++t) {
    const uint* hin = (t & 1) ? hx16b : hx16a;
    uint* hout = (t & 1) ? hx16a : hx16b;

    // ---- stage x-part from prefetch regs; issue prefetch for t+1
    *(uint4*)&hx[srow * 1024 + ((sl ^ r7) << 3)] = px0;
    *(uint4*)&hx[srow * 1024 + (((32 + sl) ^ r7) << 3)] = px1;
    if (t + 1 < TT) {
      const ushort* axp = ax + ((size_t)(gb0 + srow) * TT + (t + 1)) * NN;
      px0 = *(const uint4*)(axp + sl * 8);
      px1 = *(const uint4*)(axp + 256 + sl * 8);
    }
    bar_lds();  // B1: x-panel ready (LDS-only, no vm drain)

    f32x4 acc = {0.f, 0.f, 0.f, 0.f};
    u64 q0, q1, q2, q3;
    const uint* hrow = hin + (size_t)(gb0 + srow) * 256;

    auto xmfma = [&]() {
      #pragma unroll
      for (int ks = 0; ks < 16; ++ks) {
        const int ag = ks * 4 + kq;
        const short8 bf = *(const short8*)&hx[bbase + ((ag ^ br7) << 3)];
        acc = __builtin_amdgcn_mfma_f32_16x16x32_bf16(
            __builtin_bit_cast(short8, areg[ks]), bf, acc, 0, 0, 0);
      }
    };
    auto hload = [&]() {
      q0 = __hip_atomic_load((const u64*)(hrow + sl * 4),
                             __ATOMIC_RELAXED, __HIP_MEMORY_SCOPE_AGENT);
      q1 = __hip_atomic_load((const u64*)(hrow + sl * 4 + 2),
                             __ATOMIC_RELAXED, __HIP_MEMORY_SCOPE_AGENT);
      q2 = __hip_atomic_load((const u64*)(hrow + 128 + sl * 4),
                             __ATOMIC_RELAXED, __HIP_MEMORY_SCOPE_AGENT);
      q3 = __hip_atomic_load((const u64*)(hrow + 128 + sl * 4 + 2),
                             __ATOMIC_RELAXED, __HIP_MEMORY_SCOPE_AGENT);
    };

    if (t == 0) {
      hload();           // h0 pre-staged by prep; no sync needed
      xmfma();
    } else if (w == 0) {
      // poller wave: 2-deep pipelined tag-line poll -> broadcast -> h loads
      if (lane == 0) {
        const uint tt = (uint)t;
        const u64* tl = (const u64*)barp;
        u64 ra0, ra1, ra2, ra3, ra4, ra5, ra6, ra7;
        u64 rb0, rb1, rb2, rb3, rb4, rb5, rb6, rb7;
        #define POLL_RD(p0_,p1_,p2_,p3_,p4_,p5_,p6_,p7_)                     \
          p0_ = __hip_atomic_load(tl + 0, __ATOMIC_RELAXED,                  \
                                  __HIP_MEMORY_SCOPE_AGENT);                 \
          p1_ = __hip_atomic_load(tl + 1, __ATOMIC_RELAXED,                  \
                                  __HIP_MEMORY_SCOPE_AGENT);                 \
          p2_ = __hip_atomic_load(tl + 2, __ATOMIC_RELAXED,                  \
                                  __HIP_MEMORY_SCOPE_AGENT);                 \
          p3_ = __hip_atomic_load(tl + 3, __ATOMIC_RELAXED,                  \
                                  __HIP_MEMORY_SCOPE_AGENT);                 \
          p4_ = __hip_atomic_load(tl + 4, __ATOMIC_RELAXED,                  \
                                  __HIP_MEMORY_SCOPE_AGENT);                 \
          p5_ = __hip_atomic_load(tl + 5, __ATOMIC_RELAXED,                  \
                                  __HIP_MEMORY_SCOPE_AGENT);                 \
          p6_ = __hip_atomic_load(tl + 6, __ATOMIC_RELAXED,                  \
                                  __HIP_MEMORY_SCOPE_AGENT);                 \
          p7_ = __hip_atomic_load(tl + 7, __ATOMIC_RELAXED,                  \
                                  __HIP_MEMORY_SCOPE_AGENT)
        #define POLL_OK(p0_,p1_,p2_,p3_,p4_,p5_,p6_,p7_)                     \
          (((uint)p0_ >= tt) & ((uint)(p0_ >> 32) >= tt) &                   \
           ((uint)p1_ >= tt) & ((uint)(p1_ >> 32) >= tt) &                   \
           ((uint)p2_ >= tt) & ((uint)(p2_ >> 32) >= tt) &                   \
           ((uint)p3_ >= tt) & ((uint)(p3_ >> 32) >= tt) &                   \
           ((uint)p4_ >= tt) & ((uint)(p4_ >> 32) >= tt) &                   \
           ((uint)p5_ >= tt) & ((uint)(p5_ >> 32) >= tt) &                   \
           ((uint)p6_ >= tt) & ((uint)(p6_ >> 32) >= tt) &                   \
           ((uint)p7_ >= tt) & ((uint)(p7_ >> 32) >= tt))
        POLL_RD(ra0, ra1, ra2, ra3, ra4, ra5, ra6, ra7);
        int spins = 0;
        for (;;) {
          POLL_RD(rb0, rb1, rb2, rb3, rb4, rb5, rb6, rb7);
          if (POLL_OK(ra0, ra1, ra2, ra3, ra4, ra5, ra6, ra7)) break;
          if (++spins > (1 << 20)) break;  // fail fast, never hang
          POLL_RD(ra0, ra1, ra2, ra3, ra4, ra5, ra6, ra7);
          if (POLL_OK(rb0, rb1, rb2, rb3, rb4, rb5, rb6, rb7)) break;
          if (++spins > (1 << 20)) break;
        }
        #undef POLL_RD
        #undef POLL_OK
        __hip_atomic_store(&step_flag, (unsigned)t, __ATOMIC_RELEASE,
                           __HIP_MEMORY_SCOPE_WORKGROUP);
      }
      asm volatile("" ::: "memory");  // loads stay below the poll
      hload();
      xmfma();
    } else {
      // worker waves: MFMAs overlap the poll; then flag -> loads
      xmfma();
      if (lane == 0) {
        while (__hip_atomic_load(&step_flag, __ATOMIC_ACQUIRE,
                                 __HIP_MEMORY_SCOPE_WORKGROUP) < (unsigned)t) {}
      }
      asm volatile("" ::: "memory");  // loads stay below the flag gate
      hload();
    }

    // ---- stage h-part (ds_write waits on loads via data dependency)
    {
      uint4 p0, p1;
      p0.x = (uint)q0; p0.y = (uint)(q0 >> 32);
      p0.z = (uint)q1; p0.w = (uint)(q1 >> 32);
      p1.x = (uint)q2; p1.y = (uint)(q2 >> 32);
      p1.z = (uint)q3; p1.w = (uint)(q3 >> 32);
      *(uint4*)&hx[srow * 1024 + (((64 + sl) ^ r7) << 3)] = p0;
      *(uint4*)&hx[srow * 1024 + (((96 + sl) ^ r7) << 3)] = p1;
    }
    bar_lds();  // B2: h-panel ready (LDS-only, no vm drain)

    // ---- h-half MFMAs
    #pragma unroll
    for (int ks = 16; ks < 32; ++ks) {
      const int ag = ks * 4 + kq;
      const short8 bf = *(const short8*)&hx[bbase + ((ag ^ br7) << 3)];
      acc = __builtin_amdgcn_mfma_f32_16x16x32_bf16(
          __builtin_bit_cast(short8, areg[ks]), bf, acc, 0, 0, 0);
    }

    // ---- in-lane LSTM cell; publish h; tagged-store signal
    {
      const float ig = sigm_(acc[0] + bgi);
      const float fg = sigm_(acc[1] + bgf);
      const float gg = tanh_(acc[2] + bgg);
      const float og = sigm_(acc[3] + bgo);
      const float cn = fg * c_reg + ig * gg;
      const float hn = og * tanh_(cn);
      c_reg = cn;
      const float hp_ = __shfl_xor(hn, 16);   // partner col (kq^1)
      if (!(lane & 16)) {                     // kq even lanes store the pair
        __hip_atomic_store(hout + (size_t)(gb0 + eb) * 256 + (ecol >> 1),
                           pk2(hn, hp_),
                           __ATOMIC_RELAXED, __HIP_MEMORY_SCOPE_AGENT);
      }
      asm volatile("s_waitcnt vmcnt(0)" ::: "memory");  // wave's h at MALL
      if (lane == 0) {
        const unsigned old = __hip_atomic_fetch_add(
            &warr, 1u, __ATOMIC_ACQ_REL, __HIP_MEMORY_SCOPE_WORKGROUP);
        if (old == 8u * (unsigned)t + 7u)     // last wave: plain tag store
          __hip_atomic_store(barp + jt, (unsigned)(t + 1), __ATOMIC_RELAXED,
                             __HIP_MEMORY_SCOPE_AGENT);
      }
      enc[((size_t)(gb0 + eb) * TT + t) * HH + ecol] = hn;  // never drained
    }
  }
}

extern "C" void kernel_launch(void* const* d_in, const int* in_sizes, int n_in,
                              void* d_out, int out_size, void* d_ws, size_t ws_size,
                              hipStream_t stream) {
  const float* x      = (const float*)d_in[0];
  const float* h0     = (const float*)d_in[1];
  const float* c0     = (const float*)d_in[2];
  const float* attn_w = (const float*)d_in[3];
  // d_in[4] = attn_b: softmax-shift-invariant -> unused
  const float* w_ih   = (const float*)d_in[5];
  const float* w_hh   = (const float*)d_in[6];
  const float* b_ih   = (const float*)d_in[7];
  const float* b_hh   = (const float*)d_in[8];

  float* attn_out = (float*)d_out;                         // (B,T,N)
  float* enc_out  = (float*)d_out + (size_t)BB * TT * NN;  // (B,T,H)
  // borrow the attn output region for bf16 ax (64 MB of 128 MB) until bcast
  ushort* ax = (ushort*)d_out;

  char* ws = (char*)d_ws;
  float*    a_ws  = (float*)(ws);                    // 512 KB
  ushort*   W2_ws = (ushort*)(ws + 0x80000);         // 4 MB
  float*    bg_ws = (float*)(ws + 0x480000);         // 8 KB
  uint*     hx16a = (uint*)(ws + 0x482000);          // 256 KB
  uint*     hx16b = (uint*)(ws + 0x4C2000);          // 256 KB
  unsigned* bar   = (unsigned*)(ws + 0x502000);      // 4 KB (16 x 256B)

  prep_kernel<<<8192, 256, 0, stream>>>(w_ih, w_hh, b_ih, b_hh, h0,
                                        W2_ws, bg_ws, hx16a, bar);
  attn_kernel<<<BB, 256, 0, stream>>>(x, attn_w, a_ws, ax);

  {
    dim3 grid(256), block(512);
    void* args[] = {(void*)&ax, (void*)&W2_ws, (void*)&bg_ws, (void*)&c0,
                    (void*)&hx16a, (void*)&hx16b, (void*)&enc_out,
                    (void*)&bar};
    hipLaunchCooperativeKernel((void*)lstm_persistent, grid, block, args, 0,
                               stream);
  }

  bcast_kernel<<<32768, 256, 0, stream>>>(a_ws, attn_out);
}

// Round 16
// 830.911 us; speedup vs baseline: 1.4399x; 1.0360x over previous
//
#include <hip/hip_runtime.h>

#define BB 256
#define TT 256
#define NN 512
#define HH 512

typedef short short8 __attribute__((ext_vector_type(8)));
typedef float f32x4 __attribute__((ext_vector_type(4)));
typedef unsigned long long u64;

static __device__ __forceinline__ ushort f2bf(float f) {
  uint b = __builtin_bit_cast(uint, f);
  b += 0x7FFFu + ((b >> 16) & 1u);
  return (ushort)(b >> 16);
}
static __device__ __forceinline__ uint pk2(float lo, float hi) {
  return (uint)f2bf(lo) | ((uint)f2bf(hi) << 16);
}
static __device__ __forceinline__ float sigm_(float x) {
  return 1.0f / (1.0f + exp2f(-1.4426950408889634f * x));
}
static __device__ __forceinline__ float tanh_(float x) {
  return 2.0f / (1.0f + exp2f(-2.8853900817779268f * x)) - 1.0f;
}
// raw barrier: LDS ordering only (no vmcnt drain)
static __device__ __forceinline__ void bar_lds() {
  asm volatile("s_waitcnt lgkmcnt(0)" ::: "memory");
  __builtin_amdgcn_s_barrier();
}

// ---------------------------------------------------------------------------
// Prep: W2 = [w_ih | w_hh] bf16 (2048 x 1024), b_gate = b_ih + b_hh,
// h0 packed bf16x2 -> hx16a, zero padded barrier counters (every launch).
// ---------------------------------------------------------------------------
__global__ __launch_bounds__(256) void prep_kernel(
    const float* __restrict__ w_ih, const float* __restrict__ w_hh,
    const float* __restrict__ b_ih, const float* __restrict__ b_hh,
    const float* __restrict__ h0,
    ushort* __restrict__ W2, float* __restrict__ bgate,
    uint* __restrict__ hx16a, unsigned* __restrict__ bar) {
  int idx = blockIdx.x * 256 + threadIdx.x;
  if (idx < 2048 * 1024) {
    int row = idx >> 10;
    int k = idx & 1023;
    float v = (k < NN) ? w_ih[row * NN + k] : w_hh[row * HH + (k - NN)];
    W2[idx] = f2bf(v);
  }
  if (idx < 2048) bgate[idx] = b_ih[idx] + b_hh[idx];
  if (idx < BB * HH / 2) hx16a[idx] = pk2(h0[2 * idx], h0[2 * idx + 1]);
  if (idx < 16 * 64) bar[idx] = 0u;
}

// ---------------------------------------------------------------------------
// Attention + ax precompute (a = softmax_n(proj_x), timestep-invariant by
// softmax shift invariance). Pass 2 writes bf16 ax into the borrowed
// attentions output region; attn_out itself written by bcast_kernel.
// ---------------------------------------------------------------------------
__global__ __launch_bounds__(256) void attn_kernel(
    const float* __restrict__ x, const float* __restrict__ attn_w,
    float* __restrict__ a_out, ushort* __restrict__ ax) {
  __shared__ float wx[TT];
  __shared__ float as[NN];
  __shared__ float red[8];
  const int b = blockIdx.x;
  const int tid = threadIdx.x;
  wx[tid] = attn_w[2 * HH + tid];
  __syncthreads();

  const float* xb = x + (size_t)b * TT * NN;
  float p0 = 0.0f, p1 = 0.0f;
  for (int t = 0; t < TT; ++t) {
    float w = wx[t];
    p0 += xb[t * NN + tid] * w;
    p1 += xb[t * NN + 256 + tid] * w;
  }

  const int lane = tid & 63, wv = tid >> 6;
  float m = fmaxf(p0, p1);
  #pragma unroll
  for (int o = 32; o; o >>= 1) m = fmaxf(m, __shfl_xor(m, o));
  if (lane == 0) red[wv] = m;
  __syncthreads();
  m = fmaxf(fmaxf(red[0], red[1]), fmaxf(red[2], red[3]));
  float e0 = expf(p0 - m), e1 = expf(p1 - m);
  float s = e0 + e1;
  #pragma unroll
  for (int o = 32; o; o >>= 1) s += __shfl_xor(s, o);
  if (lane == 0) red[4 + wv] = s;
  __syncthreads();
  s = red[4] + red[5] + red[6] + red[7];
  float inv = 1.0f / s;
  float a0 = e0 * inv, a1 = e1 * inv;
  a_out[b * NN + tid] = a0;
  a_out[b * NN + 256 + tid] = a1;
  as[tid] = a0;
  as[tid + 256] = a1;
  __syncthreads();

  const float aa0 = as[tid * 2], aa1 = as[tid * 2 + 1];
  ushort* axb = ax + (size_t)b * TT * NN;
  for (int t = 0; t < TT; ++t) {
    const float2 xv = *(const float2*)(xb + t * NN + tid * 2);
    *(uint*)(axb + t * NN + tid * 2) = pk2(aa0 * xv.x, aa1 * xv.y);
  }
}

// ---------------------------------------------------------------------------
// Final: broadcast a over t into the attentions output.
// ---------------------------------------------------------------------------
__global__ __launch_bounds__(256) void bcast_kernel(
    const float* __restrict__ a, float* __restrict__ attn_out) {
  const size_t idx = (size_t)blockIdx.x * 256 + threadIdx.x;
  const int n4 = (int)(idx & 127);
  const int t = (int)((idx >> 7) & 255);
  const int b = (int)(idx >> 15);
  const float4 v = *(const float4*)(a + b * NN + n4 * 4);
  *(float4*)(attn_out + (((size_t)b * TT + t) * NN + n4 * 4)) = v;
}

// ---------------------------------------------------------------------------
// Persistent LSTM v10 (session champion, 835.5us total / ~815us lstm).
// Structure: 256 blocks (bg = blockIdx&15 -> one XCD per group), 512 threads
// (8 waves). W2 slice register-resident (128 rows/block, 32 f32x4 frags/lane).
// c register-resident. Per-lane in-lane LSTM cell (operand-swapped MFMA puts
// all 4 gates of one (batch,col) in one lane's acc[0..3]).
// Sync: relaxed agent atomics only (no cache-flushing fences); single global
// poller per block + LDS flag broadcast; per-wave vmcnt-ack + LDS warr
// aggregation -> ONE global signal add per block-step; x-half MFMAs overlap
// the poll; LDS-only barriers (no vmcnt drain); x prefetched one step ahead.
// Structural floor analysis (rounds 11-15, six falsified attack theories):
// per-step cross-CU all-to-all through MALL (~2 visibility hops) + 8-wave
// LDS panel redistribution + max-of-16-blocks join jitter ~= 7.7K cy/step.
// ---------------------------------------------------------------------------
__global__ __launch_bounds__(512, 2) void lstm_persistent(
    const ushort* __restrict__ ax,   // (B,T,N) bf16 = a*x
    const ushort* __restrict__ W2,   // (2048,1024) bf16
    const float* __restrict__ bgate, // (2048)
    const float* __restrict__ c0,    // (B,H)
    uint* __restrict__ hx16a, uint* __restrict__ hx16b,  // (B, H/2) bf16x2
    float* __restrict__ enc,         // (B,T,H)
    unsigned* __restrict__ bar) {
  __shared__ ushort hx[16 * 1024];  // 32 KB panel [16 batch][1024 k], swizzled
  __shared__ unsigned warr;         // monotonic wave-arrive counter
  __shared__ unsigned step_flag;    // poll broadcast (monotonic)

  const int tid = threadIdx.x;
  const int lane = tid & 63;
  const int w = tid >> 6;
  const int bg = blockIdx.x & 15;   // XCD-local group
  const int jt = blockIdx.x >> 4;
  const int gb0 = bg * 16;
  unsigned* const barp = bar + bg * 64;  // 256B-padded counter

  if (tid == 0) { warr = 0u; step_flag = 0u; }

  // ---- W2 A-fragments: areg[i] = k-chunk i (uniform across lanes)
  f32x4 areg[32];
  {
    const int r = lane & 15;
    const int grow = (r & 3) * 512 + jt * 32 + w * 4 + (r >> 2);
    const ushort* wp = W2 + (size_t)grow * 1024 + ((lane >> 4) << 3);
    #pragma unroll
    for (int i = 0; i < 32; ++i) {
      areg[i] = *(const f32x4*)(wp + (i << 5));
      asm volatile("" : "+v"(areg[i]));
    }
  }

  // ---- staging geometry: thread = (srow 0..15, sl 0..31)
  const int srow = tid >> 5;
  const int sl = tid & 31;
  const int r7 = srow & 7;

  // ---- per-lane output geometry: (batch eb, col ecol), 4 gates in acc[0..3]
  const int eb = lane & 15;
  const int kq = lane >> 4;
  const int ecol = jt * 32 + w * 4 + kq;
  const float bgi = bgate[ecol];
  const float bgf = bgate[512 + ecol];
  const float bgg = bgate[1024 + ecol];
  const float bgo = bgate[1536 + ecol];
  float c_reg = c0[(size_t)(gb0 + eb) * HH + ecol];

  // ---- MFMA B-read geometry (proven per-iteration XOR addressing)
  const int bbase = (lane & 15) * 1024;
  const int br7 = (lane & 15) & 7;

  // ---- x prefetch for t=0
  uint4 px0, px1;
  {
    const ushort* axp = ax + ((size_t)(gb0 + srow) * TT + 0) * NN;
    px0 = *(const uint4*)(axp + sl * 8);
    px1 = *(const uint4*)(axp + 256 + sl * 8);
  }

  for (int t = 0; t < TT; ++t) {
    const uint* hin = (t & 1) ? hx16b : hx16a;
    uint* hout = (t & 1) ? hx16a : hx16b;

    // ---- stage x-part from prefetch regs; issue prefetch for t+1
    *(uint4*)&hx[srow * 1024 + ((sl ^ r7) << 3)] = px0;
    *(uint4*)&hx[srow * 1024 + (((32 + sl) ^ r7) << 3)] = px1;
    if (t + 1 < TT) {
      const ushort* axp = ax + ((size_t)(gb0 + srow) * TT + (t + 1)) * NN;
      px0 = *(const uint4*)(axp + sl * 8);
      px1 = *(const uint4*)(axp + 256 + sl * 8);
    }
    bar_lds();  // B1: x-panel ready (LDS-only, no vm drain)

    f32x4 acc = {0.f, 0.f, 0.f, 0.f};
    u64 q0, q1, q2, q3;
    const uint* hrow = hin + (size_t)(gb0 + srow) * 256;

    auto xmfma = [&]() {
      #pragma unroll
      for (int ks = 0; ks < 16; ++ks) {
        const int ag = ks * 4 + kq;
        const short8 bf = *(const short8*)&hx[bbase + ((ag ^ br7) << 3)];
        acc = __builtin_amdgcn_mfma_f32_16x16x32_bf16(
            __builtin_bit_cast(short8, areg[ks]), bf, acc, 0, 0, 0);
      }
    };
    auto hload = [&]() {
      q0 = __hip_atomic_load((const u64*)(hrow + sl * 4),
                             __ATOMIC_RELAXED, __HIP_MEMORY_SCOPE_AGENT);
      q1 = __hip_atomic_load((const u64*)(hrow + sl * 4 + 2),
                             __ATOMIC_RELAXED, __HIP_MEMORY_SCOPE_AGENT);
      q2 = __hip_atomic_load((const u64*)(hrow + 128 + sl * 4),
                             __ATOMIC_RELAXED, __HIP_MEMORY_SCOPE_AGENT);
      q3 = __hip_atomic_load((const u64*)(hrow + 128 + sl * 4 + 2),
                             __ATOMIC_RELAXED, __HIP_MEMORY_SCOPE_AGENT);
    };

    if (t == 0) {
      hload();           // h0 pre-staged by prep; no sync needed
      xmfma();
    } else if (w == 0) {
      // poller wave: detect -> broadcast -> issue h loads -> MFMAs cover them
      if (lane == 0) {
        const unsigned target = 16u * (unsigned)t;
        while (__hip_atomic_load(barp, __ATOMIC_RELAXED,
                                 __HIP_MEMORY_SCOPE_AGENT) < target)
          __builtin_amdgcn_s_sleep(1);
        __hip_atomic_store(&step_flag, (unsigned)t, __ATOMIC_RELEASE,
                           __HIP_MEMORY_SCOPE_WORKGROUP);
      }
      asm volatile("" ::: "memory");  // loads stay below the poll
      hload();
      xmfma();
    } else {
      // worker waves: MFMAs overlap the poll; then flag -> loads
      xmfma();
      if (lane == 0) {
        while (__hip_atomic_load(&step_flag, __ATOMIC_ACQUIRE,
                                 __HIP_MEMORY_SCOPE_WORKGROUP) < (unsigned)t) {}
      }
      asm volatile("" ::: "memory");  // loads stay below the flag gate
      hload();
    }

    // ---- stage h-part (ds_write waits on loads via data dependency)
    {
      uint4 p0, p1;
      p0.x = (uint)q0; p0.y = (uint)(q0 >> 32);
      p0.z = (uint)q1; p0.w = (uint)(q1 >> 32);
      p1.x = (uint)q2; p1.y = (uint)(q2 >> 32);
      p1.z = (uint)q3; p1.w = (uint)(q3 >> 32);
      *(uint4*)&hx[srow * 1024 + (((64 + sl) ^ r7) << 3)] = p0;
      *(uint4*)&hx[srow * 1024 + (((96 + sl) ^ r7) << 3)] = p1;
    }
    bar_lds();  // B2: h-panel ready (LDS-only, no vm drain)

    // ---- h-half MFMAs
    #pragma unroll
    for (int ks = 16; ks < 32; ++ks) {
      const int ag = ks * 4 + kq;
      const short8 bf = *(const short8*)&hx[bbase + ((ag ^ br7) << 3)];
      acc = __builtin_amdgcn_mfma_f32_16x16x32_bf16(
          __builtin_bit_cast(short8, areg[ks]), bf, acc, 0, 0, 0);
    }

    // ---- in-lane LSTM cell; publish h; combined arrive
    {
      const float ig = sigm_(acc[0] + bgi);
      const float fg = sigm_(acc[1] + bgf);
      const float gg = tanh_(acc[2] + bgg);
      const float og = sigm_(acc[3] + bgo);
      const float cn = fg * c_reg + ig * gg;
      const float hn = og * tanh_(cn);
      c_reg = cn;
      const float hp_ = __shfl_xor(hn, 16);   // partner col (kq^1)
      if (!(lane & 16)) {                     // kq even lanes store the pair
        __hip_atomic_store(hout + (size_t)(gb0 + eb) * 256 + (ecol >> 1),
                           pk2(hn, hp_),
                           __ATOMIC_RELAXED, __HIP_MEMORY_SCOPE_AGENT);
      }
      asm volatile("s_waitcnt vmcnt(0)" ::: "memory");  // wave's h at MALL
      if (lane == 0) {
        const unsigned old = __hip_atomic_fetch_add(
            &warr, 1u, __ATOMIC_ACQ_REL, __HIP_MEMORY_SCOPE_WORKGROUP);
        if (old == 8u * (unsigned)t + 7u)     // last of 8 waves: one global add
          __hip_atomic_fetch_add(barp, 1u, __ATOMIC_RELAXED,
                                 __HIP_MEMORY_SCOPE_AGENT);
      }
      enc[((size_t)(gb0 + eb) * TT + t) * HH + ecol] = hn;  // never drained
    }
  }
}

extern "C" void kernel_launch(void* const* d_in, const int* in_sizes, int n_in,
                              void* d_out, int out_size, void* d_ws, size_t ws_size,
                              hipStream_t stream) {
  const float* x      = (const float*)d_in[0];
  const float* h0     = (const float*)d_in[1];
  const float* c0     = (const float*)d_in[2];
  const float* attn_w = (const float*)d_in[3];
  // d_in[4] = attn_b: softmax-shift-invariant -> unused
  const float* w_ih   = (const float*)d_in[5];
  const float* w_hh   = (const float*)d_in[6];
  const float* b_ih   = (const float*)d_in[7];
  const float* b_hh   = (const float*)d_in[8];

  float* attn_out = (float*)d_out;                         // (B,T,N)
  float* enc_out  = (float*)d_out + (size_t)BB * TT * NN;  // (B,T,H)
  // borrow the attn output region for bf16 ax (64 MB of 128 MB) until bcast
  ushort* ax = (ushort*)d_out;

  char* ws = (char*)d_ws;
  float*    a_ws  = (float*)(ws);                    // 512 KB
  ushort*   W2_ws = (ushort*)(ws + 0x80000);         // 4 MB
  float*    bg_ws = (float*)(ws + 0x480000);         // 8 KB
  uint*     hx16a = (uint*)(ws + 0x482000);          // 256 KB
  uint*     hx16b = (uint*)(ws + 0x4C2000);          // 256 KB
  unsigned* bar   = (unsigned*)(ws + 0x502000);      // 4 KB (16 x 256B)

  prep_kernel<<<8192, 256, 0, stream>>>(w_ih, w_hh, b_ih, b_hh, h0,
                                        W2_ws, bg_ws, hx16a, bar);
  attn_kernel<<<BB, 256, 0, stream>>>(x, attn_w, a_ws, ax);

  {
    dim3 grid(256), block(512);
    void* args[] = {(void*)&ax, (void*)&W2_ws, (void*)&bg_ws, (void*)&c0,
                    (void*)&hx16a, (void*)&hx16b, (void*)&enc_out,
                    (void*)&bar};
    hipLaunchCooperativeKernel((void*)lstm_persistent, grid, block, args, 0,
                               stream);
  }

  bcast_kernel<<<32768, 256, 0, stream>>>(a_ws, attn_out);
}